// Round 1
// baseline (888.237 us; speedup 1.0000x reference)
//
#include <hip/hip_runtime.h>

#define NE 8
#define DD 1024
#define HH 2816
#define TT 16384
#define MT (TT / 128 + NE)  // 136 static M-tiles (128-row)

constexpr int NJA = MT * (HH / 128);  // 2992 jobs, %8==0 -> bijective XCD swizzle
constexpr int NJB = MT * (DD / 128);  // 1088 jobs, %8==0

typedef __bf16 bf16;
typedef __bf16 bf16x4 __attribute__((ext_vector_type(4)));
typedef __bf16 bf16x8 __attribute__((ext_vector_type(8)));
typedef float f32x4 __attribute__((ext_vector_type(4)));

// ---- workspace layout (bytes), unchanged ----
constexpr size_t HBUF_E = (size_t)TT * HH;
constexpr size_t XN = (size_t)TT * DD;
constexpr size_t WN = (size_t)NE * HH * DD;
constexpr size_t XB_OFF = HBUF_E * 2;
constexpr size_t W1B_OFF = XB_OFF + XN * 2;
constexpr size_t W3B_OFF = W1B_OFF + WN * 2;

__device__ __forceinline__ void gld16(const void* g, void* l) {
  __builtin_amdgcn_global_load_lds(
      (const __attribute__((address_space(1))) void*)g,
      (__attribute__((address_space(3))) void*)l, 16, 0, 0);
}

__device__ __forceinline__ f32x4 mfma16(bf16x8 a, bf16x8 b, f32x4 c) {
  return __builtin_amdgcn_mfma_f32_16x16x32_bf16(a, b, c, 0, 0, 0);
}

// raw barrier (NO implicit vmcnt(0) drain, unlike __syncthreads) + compiler fence
#define BARRIER()                      \
  do {                                 \
    __builtin_amdgcn_s_barrier();      \
    asm volatile("" ::: "memory");     \
  } while (0)

// fp32 -> bf16 elementwise convert, 4 elems/thread
__global__ __launch_bounds__(256) void cvt_bf16_k(const float4* __restrict__ in,
                                                  bf16x4* __restrict__ out, int n4) {
  int i = blockIdx.x * 256 + threadIdx.x;
  if (i < n4) {
    float4 v = in[i];
    bf16x4 o;
    o[0] = (bf16)v.x; o[1] = (bf16)v.y; o[2] = (bf16)v.z; o[3] = (bf16)v.w;
    out[i] = o;
  }
}

struct TileInfo { int e, row0, rv; };
__device__ __forceinline__ TileInfo find_tile(const int* __restrict__ cnts, int t) {
  TileInfo ti; ti.e = -1; ti.row0 = 0; ti.rv = 0;
  int off = 0;
#pragma unroll
  for (int i = 0; i < NE; ++i) {
    int c = cnts[i];
    int tl = (c + 127) >> 7;
    if (ti.e < 0) {
      if (t < tl) {
        ti.e = i;
        ti.row0 = off + (t << 7);
        int rv = c - (t << 7);
        ti.rv = rv > 128 ? 128 : rv;
      } else {
        t -= tl;
      }
    }
    off += c;
  }
  return ti;
}

// ============================================================================
// Kernel A: h = silu(x@w1[e]^T) * (x@w3[e]^T)
// BM=128, BN=128 (per matrix), BK=64. 512 thr = 8 waves (2M x 4N).
// Triple-buffered LDS (144 KB), counted vmcnt(6) (never 0 in steady state),
// XOR-swizzled LDS (pre-swizzled global src, linear gld_lds dest), setprio.
// Per wave: 64x32 of each of h1,h3 -> acc1[4][2], acc3[4][2].
// ============================================================================
__global__ __launch_bounds__(512, 2) void swiglu_gemm_k(
    const bf16* __restrict__ x, const bf16* __restrict__ w1,
    const bf16* __restrict__ w3, const int* __restrict__ cnts,
    bf16* __restrict__ hbuf) {
  constexpr int NKT = DD / 64;  // 16 K-tiles

  // bijective XCD swizzle: contiguous job chunk per XCD (NJA % 8 == 0)
  int lin = blockIdx.x;
  lin = (lin & 7) * (NJA / 8) + (lin >> 3);
  const int tile = lin % MT;          // tile-minor: same n0 slab stays L2-hot
  const int n0 = (lin / MT) * 128;
  TileInfo ti = find_tile(cnts, tile);
  if (ti.e < 0) return;

  const bf16* w1e = w1 + (size_t)ti.e * HH * DD;
  const bf16* w3e = w3 + (size_t)ti.e * HH * DD;
  const bf16* xb = x + (size_t)ti.row0 * DD;

  __shared__ bf16 sA[3][128 * 64];
  __shared__ bf16 sB1[3][128 * 64];
  __shared__ bf16 sB3[3][128 * 64];

  const int tid = threadIdx.x;
  const int lane = tid & 63, wave = tid >> 6;
  const int wm = wave >> 2, wn = wave & 3;
  const int lr = lane & 15, lkg = lane >> 4;

  // ---- staging addresses: linear LDS dest, inverse-swizzled global source ----
  const int r8 = tid >> 3;                         // row within 64-row sweep
  const int csrc = ((tid & 7) ^ (r8 & 7)) << 3;    // swizzled 8-elem chunk
  const int rvm1 = ti.rv - 1;
  const int ra0 = r8 > rvm1 ? rvm1 : r8;
  const int ra1 = (64 + r8) > rvm1 ? rvm1 : 64 + r8;
  const bf16* gA0 = xb + (size_t)ra0 * DD + csrc;
  const bf16* gA1 = xb + (size_t)ra1 * DD + csrc;
  const bf16* gB1a = w1e + (size_t)(n0 + r8) * DD + csrc;
  const bf16* gB1b = w1e + (size_t)(n0 + 64 + r8) * DD + csrc;
  const bf16* gB3a = w3e + (size_t)(n0 + r8) * DD + csrc;
  const bf16* gB3b = w3e + (size_t)(n0 + 64 + r8) * DD + csrc;
  const int d0 = tid * 8, d1 = 64 * 64 + tid * 8;

#define STAGE_A(kt, bb)                  \
  do {                                   \
    int kk = (kt) * 64;                  \
    gld16(gA0 + kk, &sA[bb][d0]);        \
    gld16(gA1 + kk, &sA[bb][d1]);        \
    gld16(gB1a + kk, &sB1[bb][d0]);      \
    gld16(gB1b + kk, &sB1[bb][d1]);      \
    gld16(gB3a + kk, &sB3[bb][d0]);      \
    gld16(gB3b + kk, &sB3[bb][d1]);      \
  } while (0)

  // ---- LDS read offsets: byte = row*128 + ((chunk ^ (row&7))<<4); row&7==lr&7 ----
  const int swz = (lkg ^ (lr & 7)) << 4;
  const int aoff = (wm * 64 + lr) * 128 + swz;  // + mt*2048, ^(ks<<6)
  const int boff = (wn * 32 + lr) * 128 + swz;  // + nt*2048, ^(ks<<6)

  f32x4 acc1[4][2], acc3[4][2];
#pragma unroll
  for (int i = 0; i < 4; ++i)
#pragma unroll
    for (int j = 0; j < 2; ++j) {
      acc1[i][j] = f32x4{0.f, 0.f, 0.f, 0.f};
      acc3[i][j] = f32x4{0.f, 0.f, 0.f, 0.f};
    }

  STAGE_A(0, 0);
  STAGE_A(1, 1);
  asm volatile("s_waitcnt vmcnt(6)" ::: "memory");  // kt0 landed, kt1 in flight
  BARRIER();

  int cur = 0;
  for (int kt = 0; kt < NKT; ++kt) {
    const bool pf = (kt + 2) < NKT;
    int nxt = cur + 2; if (nxt >= 3) nxt -= 3;
    if (pf) STAGE_A(kt + 2, nxt);  // issue-early; target buf freed last iter

    const char* pA = (const char*)sA[cur];
    const char* pB1 = (const char*)sB1[cur];
    const char* pB3 = (const char*)sB3[cur];
    bf16x8 af[4][2], f1[2][2], f3[2][2];
#pragma unroll
    for (int mt = 0; mt < 4; ++mt)
#pragma unroll
      for (int ks = 0; ks < 2; ++ks)
        af[mt][ks] = *(const bf16x8*)(pA + ((aoff + mt * 2048) ^ (ks << 6)));
#pragma unroll
    for (int nt = 0; nt < 2; ++nt)
#pragma unroll
      for (int ks = 0; ks < 2; ++ks) {
        f1[nt][ks] = *(const bf16x8*)(pB1 + ((boff + nt * 2048) ^ (ks << 6)));
        f3[nt][ks] = *(const bf16x8*)(pB3 + ((boff + nt * 2048) ^ (ks << 6)));
      }
    __builtin_amdgcn_s_setprio(1);
#pragma unroll
    for (int ks = 0; ks < 2; ++ks)
#pragma unroll
      for (int mt = 0; mt < 4; ++mt)
#pragma unroll
        for (int nt = 0; nt < 2; ++nt) {
          acc1[mt][nt] = mfma16(af[mt][ks], f1[nt][ks], acc1[mt][nt]);
          acc3[mt][nt] = mfma16(af[mt][ks], f3[nt][ks], acc3[mt][nt]);
        }
    __builtin_amdgcn_s_setprio(0);
    // counted wait: guarantee PREVIOUS iter's stages landed (next iter reads them);
    // lgkmcnt(0) pins this iter's ds_reads complete before the barrier (overwrite safety)
    if (pf) asm volatile("s_waitcnt vmcnt(6) lgkmcnt(0)" ::: "memory");
    else    asm volatile("s_waitcnt vmcnt(0) lgkmcnt(0)" ::: "memory");
    BARRIER();
    cur = (cur + 1 == 3) ? 0 : cur + 1;
  }
#undef STAGE_A

  const int rq = (lane >> 4) << 2;
#pragma unroll
  for (int mt = 0; mt < 4; ++mt)
#pragma unroll
    for (int r = 0; r < 4; ++r) {
      int row = wm * 64 + mt * 16 + rq + r;
      if (row < ti.rv) {
        size_t base = (size_t)(ti.row0 + row) * HH + n0 + wn * 32 + lr;
#pragma unroll
        for (int nt = 0; nt < 2; ++nt) {
          float a = acc1[mt][nt][r], b = acc3[mt][nt][r];
          hbuf[base + nt * 16] = (bf16)(a / (1.f + __expf(-a)) * b);
        }
      }
    }
}

// ============================================================================
// Kernel B: out = h @ w2[e]^T. Same template minus the second B matrix.
// BM=128, BN=128, BK=64, triple-buffered (96 KB), vmcnt(4). fp32 out.
// ============================================================================
__global__ __launch_bounds__(512, 2) void down_gemm_k(
    const bf16* __restrict__ hbuf, const bf16* __restrict__ w2,
    const int* __restrict__ cnts, float* __restrict__ out) {
  constexpr int NKT = HH / 64;  // 44 K-tiles

  int lin = blockIdx.x;
  lin = (lin & 7) * (NJB / 8) + (lin >> 3);  // NJB % 8 == 0
  const int tile = lin % MT;                 // chunk = 136 = one full n0 slab/XCD
  const int n0 = (lin / MT) * 128;
  TileInfo ti = find_tile(cnts, tile);
  if (ti.e < 0) return;

  const bf16* w2e = w2 + (size_t)ti.e * DD * HH;
  const bf16* hb = hbuf + (size_t)ti.row0 * HH;

  __shared__ bf16 sA[3][128 * 64];
  __shared__ bf16 sB[3][128 * 64];

  const int tid = threadIdx.x;
  const int lane = tid & 63, wave = tid >> 6;
  const int wm = wave >> 2, wn = wave & 3;
  const int lr = lane & 15, lkg = lane >> 4;

  const int r8 = tid >> 3;
  const int csrc = ((tid & 7) ^ (r8 & 7)) << 3;
  const int rvm1 = ti.rv - 1;
  const int ra0 = r8 > rvm1 ? rvm1 : r8;
  const int ra1 = (64 + r8) > rvm1 ? rvm1 : 64 + r8;
  const bf16* gA0 = hb + (size_t)ra0 * HH + csrc;
  const bf16* gA1 = hb + (size_t)ra1 * HH + csrc;
  const bf16* gBa = w2e + (size_t)(n0 + r8) * HH + csrc;
  const bf16* gBb = w2e + (size_t)(n0 + 64 + r8) * HH + csrc;
  const int d0 = tid * 8, d1 = 64 * 64 + tid * 8;

#define STAGE_B(kt, bb)                 \
  do {                                  \
    int kk = (kt) * 64;                 \
    gld16(gA0 + kk, &sA[bb][d0]);       \
    gld16(gA1 + kk, &sA[bb][d1]);       \
    gld16(gBa + kk, &sB[bb][d0]);       \
    gld16(gBb + kk, &sB[bb][d1]);       \
  } while (0)

  const int swz = (lkg ^ (lr & 7)) << 4;
  const int aoff = (wm * 64 + lr) * 128 + swz;
  const int boff = (wn * 32 + lr) * 128 + swz;

  f32x4 acc[4][2];
#pragma unroll
  for (int i = 0; i < 4; ++i)
#pragma unroll
    for (int j = 0; j < 2; ++j) acc[i][j] = f32x4{0.f, 0.f, 0.f, 0.f};

  STAGE_B(0, 0);
  STAGE_B(1, 1);
  asm volatile("s_waitcnt vmcnt(4)" ::: "memory");
  BARRIER();

  int cur = 0;
  for (int kt = 0; kt < NKT; ++kt) {
    const bool pf = (kt + 2) < NKT;
    int nxt = cur + 2; if (nxt >= 3) nxt -= 3;
    if (pf) STAGE_B(kt + 2, nxt);

    const char* pA = (const char*)sA[cur];
    const char* pB = (const char*)sB[cur];
    bf16x8 af[4][2], bfm[2][2];
#pragma unroll
    for (int mt = 0; mt < 4; ++mt)
#pragma unroll
      for (int ks = 0; ks < 2; ++ks)
        af[mt][ks] = *(const bf16x8*)(pA + ((aoff + mt * 2048) ^ (ks << 6)));
#pragma unroll
    for (int nt = 0; nt < 2; ++nt)
#pragma unroll
      for (int ks = 0; ks < 2; ++ks)
        bfm[nt][ks] = *(const bf16x8*)(pB + ((boff + nt * 2048) ^ (ks << 6)));
    __builtin_amdgcn_s_setprio(1);
#pragma unroll
    for (int ks = 0; ks < 2; ++ks)
#pragma unroll
      for (int mt = 0; mt < 4; ++mt)
#pragma unroll
        for (int nt = 0; nt < 2; ++nt)
          acc[mt][nt] = mfma16(af[mt][ks], bfm[nt][ks], acc[mt][nt]);
    __builtin_amdgcn_s_setprio(0);
    if (pf) asm volatile("s_waitcnt vmcnt(4) lgkmcnt(0)" ::: "memory");
    else    asm volatile("s_waitcnt vmcnt(0) lgkmcnt(0)" ::: "memory");
    BARRIER();
    cur = (cur + 1 == 3) ? 0 : cur + 1;
  }
#undef STAGE_B

  const int rq = (lane >> 4) << 2;
#pragma unroll
  for (int mt = 0; mt < 4; ++mt)
#pragma unroll
    for (int r = 0; r < 4; ++r) {
      int row = wm * 64 + mt * 16 + rq + r;
      if (row < ti.rv) {
        size_t base = (size_t)(ti.row0 + row) * DD + n0 + wn * 32 + lr;
#pragma unroll
        for (int nt = 0; nt < 2; ++nt) out[base + nt * 16] = acc[mt][nt][r];
      }
    }
}

extern "C" void kernel_launch(void* const* d_in, const int* in_sizes, int n_in,
                              void* d_out, int out_size, void* d_ws, size_t ws_size,
                              hipStream_t stream) {
  const float* x = (const float*)d_in[0];
  const float* w1 = (const float*)d_in[1];
  const float* w2 = (const float*)d_in[2];
  const float* w3 = (const float*)d_in[3];
  const int* cnts = (const int*)d_in[4];
  float* out = (float*)d_out;

  char* ws = (char*)d_ws;
  bf16* hbuf = (bf16*)ws;
  bf16* xb = (bf16*)(ws + XB_OFF);
  bf16* w1b = (bf16*)(ws + W1B_OFF);
  bf16* w3b = (bf16*)(ws + W3B_OFF);
  bf16* w2b = w1b;  // alias: w1b dead after GEMM A, stream-serial

  hipMemsetAsync(d_out, 0, (size_t)out_size * sizeof(float), stream);

  cvt_bf16_k<<<(int)(XN / 4 / 256), 256, 0, stream>>>((const float4*)x, (bf16x4*)xb, (int)(XN / 4));
  cvt_bf16_k<<<(int)(WN / 4 / 256), 256, 0, stream>>>((const float4*)w1, (bf16x4*)w1b, (int)(WN / 4));
  cvt_bf16_k<<<(int)(WN / 4 / 256), 256, 0, stream>>>((const float4*)w3, (bf16x4*)w3b, (int)(WN / 4));

  swiglu_gemm_k<<<NJA, 512, 0, stream>>>(xb, w1b, w3b, cnts, hbuf);

  cvt_bf16_k<<<(int)(WN / 4 / 256), 256, 0, stream>>>((const float4*)w2, (bf16x4*)w2b, (int)(WN / 4));

  down_gemm_k<<<NJB, 512, 0, stream>>>(hbuf, w2b, cnts, out);
}

// Round 3
// 740.495 us; speedup vs baseline: 1.1995x; 1.1995x over previous
//
#include <hip/hip_runtime.h>

#define NE 8
#define DD 1024
#define HH 2816
#define TT 16384
#define MT (TT / 128 + NE)  // 136 static M-tiles (128-row)

constexpr int NJA = MT * (HH / 64);   // 5984 jobs, %8==0
constexpr int NJB = MT * (DD / 128);  // 1088 jobs, %8==0
constexpr int ZBLK = 64;              // tail-zero blocks appended to down_gemm grid

typedef __bf16 bf16;
typedef __bf16 bf16x4 __attribute__((ext_vector_type(4)));
typedef __bf16 bf16x8 __attribute__((ext_vector_type(8)));
typedef float f32x4 __attribute__((ext_vector_type(4)));

// ---- workspace layout (bytes), unchanged ----
constexpr size_t HBUF_E = (size_t)TT * HH;
constexpr size_t XN = (size_t)TT * DD;
constexpr size_t WN = (size_t)NE * HH * DD;
constexpr size_t XB_OFF = HBUF_E * 2;
constexpr size_t W1B_OFF = XB_OFF + XN * 2;
constexpr size_t W3B_OFF = W1B_OFF + WN * 2;

__device__ __forceinline__ void gld16(const void* g, void* l) {
  __builtin_amdgcn_global_load_lds(
      (const __attribute__((address_space(1))) void*)g,
      (__attribute__((address_space(3))) void*)l, 16, 0, 0);
}

__device__ __forceinline__ f32x4 mfma16(bf16x8 a, bf16x8 b, f32x4 c) {
  return __builtin_amdgcn_mfma_f32_16x16x32_bf16(a, b, c, 0, 0, 0);
}

#define BARRIER()                      \
  do {                                 \
    __builtin_amdgcn_s_barrier();      \
    asm volatile("" ::: "memory");     \
  } while (0)

// fused fp32->bf16 convert for x, w1, w3 in one dispatch
__global__ __launch_bounds__(256) void cvt3_k(
    const float4* __restrict__ x, const float4* __restrict__ w1,
    const float4* __restrict__ w3, bf16x4* __restrict__ xb,
    bf16x4* __restrict__ w1b, bf16x4* __restrict__ w3b) {
  constexpr int NBX = (int)(XN / 4 / 256);  // 16384
  constexpr int NBW = (int)(WN / 4 / 256);  // 22528
  int b = blockIdx.x;
  const float4* src;
  bf16x4* dst;
  int i;
  if (b < NBX) {
    src = x; dst = xb; i = b * 256 + threadIdx.x;
  } else if (b < NBX + NBW) {
    src = w1; dst = w1b; i = (b - NBX) * 256 + threadIdx.x;
  } else {
    src = w3; dst = w3b; i = (b - NBX - NBW) * 256 + threadIdx.x;
  }
  float4 v = src[i];
  bf16x4 o;
  o[0] = (bf16)v.x; o[1] = (bf16)v.y; o[2] = (bf16)v.z; o[3] = (bf16)v.w;
  dst[i] = o;
}

// single-matrix convert (w2, after GEMM A frees its alias)
__global__ __launch_bounds__(256) void cvt_bf16_k(const float4* __restrict__ in,
                                                  bf16x4* __restrict__ out, int n4) {
  int i = blockIdx.x * 256 + threadIdx.x;
  if (i < n4) {
    float4 v = in[i];
    bf16x4 o;
    o[0] = (bf16)v.x; o[1] = (bf16)v.y; o[2] = (bf16)v.z; o[3] = (bf16)v.w;
    out[i] = o;
  }
}

struct TileInfo { int e, row0, rv; };
__device__ __forceinline__ TileInfo find_tile(const int* __restrict__ cnts, int t) {
  TileInfo ti; ti.e = -1; ti.row0 = 0; ti.rv = 0;
  int off = 0;
#pragma unroll
  for (int i = 0; i < NE; ++i) {
    int c = cnts[i];
    int tl = (c + 127) >> 7;
    if (ti.e < 0) {
      if (t < tl) {
        ti.e = i;
        ti.row0 = off + (t << 7);
        int rv = c - (t << 7);
        ti.rv = rv > 128 ? 128 : rv;
      } else {
        t -= tl;
      }
    }
    off += c;
  }
  return ti;
}

// ============================================================================
// Kernel A: h = silu(x@w1[e]^T) * (x@w3[e]^T)
// BM=128, BN=64 per matrix, BK=32. 256 thr = 4 waves (2M x 2N).
// Triple-buffered LDS (48 KB -> 3 blocks/CU), counted vmcnt(4) (never 0 in
// steady state), XOR-swizzled LDS (chunk ^= (row>>1)&3; <=2-way = free),
// swapped-operand MFMA (lane holds 4 consecutive out cols -> bf16x4 stores).
// ============================================================================
__global__ __launch_bounds__(256, 3) void swiglu_gemm_k(
    const bf16* __restrict__ x, const bf16* __restrict__ w1,
    const bf16* __restrict__ w3, const int* __restrict__ cnts,
    bf16* __restrict__ hbuf) {
  constexpr int NKT = DD / 32;  // 32 K-tiles

  // bijective XCD swizzle (NJA % 8 == 0), tile-minor (weight slab L2-hot)
  int lin = blockIdx.x;
  lin = (lin & 7) * (NJA / 8) + (lin >> 3);
  const int tile = lin % MT;
  const int n0 = (lin / MT) * 64;
  TileInfo ti = find_tile(cnts, tile);
  if (ti.e < 0) return;

  const bf16* w1e = w1 + (size_t)ti.e * HH * DD;
  const bf16* w3e = w3 + (size_t)ti.e * HH * DD;
  const bf16* xb = x + (size_t)ti.row0 * DD;

  __shared__ bf16 sA[3][128 * 32];   // 8 KB / buf
  __shared__ bf16 sB1[3][64 * 32];   // 4 KB / buf
  __shared__ bf16 sB3[3][64 * 32];   // 4 KB / buf -> 48 KB total

  const int tid = threadIdx.x;
  const int lane = tid & 63, wave = tid >> 6;
  const int wm = wave >> 1, wn = wave & 1;
  const int lr = lane & 15, lkg = lane >> 4;

  // ---- staging: linear LDS dest, inverse-swizzled global source ----
  const int r8 = tid >> 2;                              // row 0..63
  const int csw = (((tid & 3) ^ ((r8 >> 1) & 3)) << 3); // swizzled col (elems)
  const int rvm1 = ti.rv - 1;
  const int ra0 = r8 > rvm1 ? rvm1 : r8;
  const int ra1 = (64 + r8) > rvm1 ? rvm1 : 64 + r8;
  const bf16* gA0 = xb + (size_t)ra0 * DD + csw;
  const bf16* gA1 = xb + (size_t)ra1 * DD + csw;
  const bf16* gB1 = w1e + (size_t)(n0 + r8) * DD + csw;
  const bf16* gB3 = w3e + (size_t)(n0 + r8) * DD + csw;
  const int d0 = tid * 8, d1 = (256 + tid) * 8;

#define STAGE_A(kt, bb)                 \
  do {                                  \
    int kk = (kt) * 32;                 \
    gld16(gA0 + kk, &sA[bb][d0]);       \
    gld16(gA1 + kk, &sA[bb][d1]);       \
    gld16(gB1 + kk, &sB1[bb][d0]);      \
    gld16(gB3 + kk, &sB3[bb][d0]);      \
  } while (0)

  // ---- LDS read: byte = row*64 + ((lkg ^ ((row>>1)&3))<<4); row&7 == lr&7 ----
  const int swz = (lkg ^ ((lr >> 1) & 3)) << 4;
  const int aoff = (wm * 64 + lr) * 64 + swz;  // + mt*1024
  const int boff = (wn * 32 + lr) * 64 + swz;  // + nt*1024

  f32x4 acc1[4][2], acc3[4][2];
#pragma unroll
  for (int i = 0; i < 4; ++i)
#pragma unroll
    for (int j = 0; j < 2; ++j) {
      acc1[i][j] = f32x4{0.f, 0.f, 0.f, 0.f};
      acc3[i][j] = f32x4{0.f, 0.f, 0.f, 0.f};
    }

  STAGE_A(0, 0);
  STAGE_A(1, 1);
  asm volatile("s_waitcnt vmcnt(4)" ::: "memory");  // kt0 landed, kt1 in flight
  BARRIER();

  int cur = 0;
  for (int kt = 0; kt < NKT; ++kt) {
    const bool pf = (kt + 2) < NKT;
    int nxt = cur + 2; if (nxt >= 3) nxt -= 3;
    if (pf) STAGE_A(kt + 2, nxt);  // issue-early; target buf freed last iter

    const char* pA = (const char*)sA[cur];
    const char* pB1 = (const char*)sB1[cur];
    const char* pB3 = (const char*)sB3[cur];
    bf16x8 af[4], f1[2], f3[2];
#pragma unroll
    for (int mt = 0; mt < 4; ++mt)
      af[mt] = *(const bf16x8*)(pA + aoff + mt * 1024);
#pragma unroll
    for (int nt = 0; nt < 2; ++nt) {
      f1[nt] = *(const bf16x8*)(pB1 + boff + nt * 1024);
      f3[nt] = *(const bf16x8*)(pB3 + boff + nt * 1024);
    }
    __builtin_amdgcn_s_setprio(1);
#pragma unroll
    for (int mt = 0; mt < 4; ++mt)
#pragma unroll
      for (int nt = 0; nt < 2; ++nt) {
        acc1[mt][nt] = mfma16(f1[nt], af[mt], acc1[mt][nt]);  // swapped operands
        acc3[mt][nt] = mfma16(f3[nt], af[mt], acc3[mt][nt]);
      }
    __builtin_amdgcn_s_setprio(0);
    // counted wait: prev stage landed before next iter reads it;
    // lgkmcnt(0): this iter's ds_reads done before barrier (buf overwritten next iter)
    if (pf) asm volatile("s_waitcnt vmcnt(4) lgkmcnt(0)" ::: "memory");
    else    asm volatile("s_waitcnt vmcnt(0) lgkmcnt(0)" ::: "memory");
    BARRIER();
    cur = (cur + 1 == 3) ? 0 : cur + 1;
  }
#undef STAGE_A

  // epilogue: swapped layout -> m = lr, n = lkg*4 + reg (4 consecutive cols)
#pragma unroll
  for (int mt = 0; mt < 4; ++mt) {
    int row = wm * 64 + mt * 16 + lr;
    if (row < ti.rv) {
      size_t base = (size_t)(ti.row0 + row) * HH + n0 + wn * 32 + (lkg << 2);
#pragma unroll
      for (int nt = 0; nt < 2; ++nt) {
        bf16x4 o;
#pragma unroll
        for (int r = 0; r < 4; ++r) {
          float a = acc1[mt][nt][r], b = acc3[mt][nt][r];
          o[r] = (bf16)(a / (1.f + __expf(-a)) * b);
        }
        *(bf16x4*)&hbuf[base + nt * 16] = o;
      }
    }
  }
}

// ============================================================================
// Kernel B: out = h @ w2[e]^T. BM=128, BN=128, BK=32, 256 thr (2M x 2N waves),
// triple-buffered (48 KB -> 3 blocks/CU), counted vmcnt(4), f32x4 stores.
// Tail blocks (>= NJB) zero the padding rows (replaces host memset).
// ============================================================================
__global__ __launch_bounds__(256, 3) void down_gemm_k(
    const bf16* __restrict__ hbuf, const bf16* __restrict__ w2,
    const int* __restrict__ cnts, float* __restrict__ out) {
  constexpr int NKT = HH / 32;  // 88 K-tiles

  int b = blockIdx.x;
  if (b >= NJB) {  // zero the padding rows [sum(cnts), TT)
    int total = 0;
#pragma unroll
    for (int e = 0; e < NE; ++e) total += cnts[e];
    size_t base4 = (size_t)total * (DD / 4);
    size_t n4 = ((size_t)TT * DD) / 4 - base4;
    f32x4* o4 = (f32x4*)out + base4;
    f32x4 z{0.f, 0.f, 0.f, 0.f};
    for (size_t i = (size_t)(b - NJB) * 256 + threadIdx.x; i < n4;
         i += (size_t)ZBLK * 256)
      o4[i] = z;
    return;
  }

  int lin = (b & 7) * (NJB / 8) + (b >> 3);  // NJB % 8 == 0
  const int tile = lin % MT;
  const int n0 = (lin / MT) * 128;
  TileInfo ti = find_tile(cnts, tile);
  if (ti.e < 0) return;

  const bf16* w2e = w2 + (size_t)ti.e * DD * HH;
  const bf16* hb = hbuf + (size_t)ti.row0 * HH;

  __shared__ bf16 sA[3][128 * 32];
  __shared__ bf16 sB[3][128 * 32];  // 48 KB total

  const int tid = threadIdx.x;
  const int lane = tid & 63, wave = tid >> 6;
  const int wm = wave >> 1, wn = wave & 1;
  const int lr = lane & 15, lkg = lane >> 4;

  const int r8 = tid >> 2;
  const int csw = (((tid & 3) ^ ((r8 >> 1) & 3)) << 3);
  const int rvm1 = ti.rv - 1;
  const int ra0 = r8 > rvm1 ? rvm1 : r8;
  const int ra1 = (64 + r8) > rvm1 ? rvm1 : 64 + r8;
  const bf16* gA0 = hb + (size_t)ra0 * HH + csw;
  const bf16* gA1 = hb + (size_t)ra1 * HH + csw;
  const bf16* gB0 = w2e + (size_t)(n0 + r8) * HH + csw;
  const bf16* gB1 = w2e + (size_t)(n0 + 64 + r8) * HH + csw;
  const int d0 = tid * 8, d1 = (256 + tid) * 8;

#define STAGE_B(kt, bb)                 \
  do {                                  \
    int kk = (kt) * 32;                 \
    gld16(gA0 + kk, &sA[bb][d0]);       \
    gld16(gA1 + kk, &sA[bb][d1]);       \
    gld16(gB0 + kk, &sB[bb][d0]);       \
    gld16(gB1 + kk, &sB[bb][d1]);       \
  } while (0)

  const int swz = (lkg ^ ((lr >> 1) & 3)) << 4;
  const int aoff = (wm * 64 + lr) * 64 + swz;
  const int boff = (wn * 64 + lr) * 64 + swz;

  f32x4 acc[4][4];
#pragma unroll
  for (int i = 0; i < 4; ++i)
#pragma unroll
    for (int j = 0; j < 4; ++j) acc[i][j] = f32x4{0.f, 0.f, 0.f, 0.f};

  STAGE_B(0, 0);
  STAGE_B(1, 1);
  asm volatile("s_waitcnt vmcnt(4)" ::: "memory");
  BARRIER();

  int cur = 0;
  for (int kt = 0; kt < NKT; ++kt) {
    const bool pf = (kt + 2) < NKT;
    int nxt = cur + 2; if (nxt >= 3) nxt -= 3;
    if (pf) STAGE_B(kt + 2, nxt);

    const char* pA = (const char*)sA[cur];
    const char* pB = (const char*)sB[cur];
    bf16x8 af[4], bfm[4];
#pragma unroll
    for (int mt = 0; mt < 4; ++mt)
      af[mt] = *(const bf16x8*)(pA + aoff + mt * 1024);
#pragma unroll
    for (int nt = 0; nt < 4; ++nt)
      bfm[nt] = *(const bf16x8*)(pB + boff + nt * 1024);
    __builtin_amdgcn_s_setprio(1);
#pragma unroll
    for (int mt = 0; mt < 4; ++mt)
#pragma unroll
      for (int nt = 0; nt < 4; ++nt)
        acc[mt][nt] = mfma16(bfm[nt], af[mt], acc[mt][nt]);  // swapped operands
    __builtin_amdgcn_s_setprio(0);
    if (pf) asm volatile("s_waitcnt vmcnt(4) lgkmcnt(0)" ::: "memory");
    else    asm volatile("s_waitcnt vmcnt(0) lgkmcnt(0)" ::: "memory");
    BARRIER();
    cur = (cur + 1 == 3) ? 0 : cur + 1;
  }
#undef STAGE_B

  // epilogue: m = lr, n = lkg*4 + reg -> one 16 B store per fragment
#pragma unroll
  for (int mt = 0; mt < 4; ++mt) {
    int row = wm * 64 + mt * 16 + lr;
    if (row < ti.rv) {
      size_t base = (size_t)(ti.row0 + row) * DD + n0 + wn * 64 + (lkg << 2);
#pragma unroll
      for (int nt = 0; nt < 4; ++nt)
        *(f32x4*)&out[base + nt * 16] = acc[mt][nt];
    }
  }
}

extern "C" void kernel_launch(void* const* d_in, const int* in_sizes, int n_in,
                              void* d_out, int out_size, void* d_ws, size_t ws_size,
                              hipStream_t stream) {
  const float* x = (const float*)d_in[0];
  const float* w1 = (const float*)d_in[1];
  const float* w2 = (const float*)d_in[2];
  const float* w3 = (const float*)d_in[3];
  const int* cnts = (const int*)d_in[4];
  float* out = (float*)d_out;

  char* ws = (char*)d_ws;
  bf16* hbuf = (bf16*)ws;
  bf16* xb = (bf16*)(ws + XB_OFF);
  bf16* w1b = (bf16*)(ws + W1B_OFF);
  bf16* w3b = (bf16*)(ws + W3B_OFF);
  bf16* w2b = w1b;  // alias: w1b dead after GEMM A, stream-serial

  constexpr int NBX = (int)(XN / 4 / 256);
  constexpr int NBW = (int)(WN / 4 / 256);

  // fused converts (x, w1, w3); no memset (down_gemm tail blocks zero padding)
  cvt3_k<<<NBX + 2 * NBW, 256, 0, stream>>>((const float4*)x, (const float4*)w1,
                                            (const float4*)w3, (bf16x4*)xb,
                                            (bf16x4*)w1b, (bf16x4*)w3b);

  swiglu_gemm_k<<<NJA, 256, 0, stream>>>(xb, w1b, w3b, cnts, hbuf);

  cvt_bf16_k<<<NBW, 256, 0, stream>>>((const float4*)w2, (bf16x4*)w2b, (int)(WN / 4));

  down_gemm_k<<<NJB + ZBLK, 256, 0, stream>>>(hbuf, w2b, cnts, out);
}